// Round 1
// baseline (7619.463 us; speedup 1.0000x reference)
//
#include <hip/hip_runtime.h>

// B=128, S=1024, F_IN=128, H=256, BB=256, F_OUT=128
#define Bn   128
#define Sn   1024
#define FIN  128
#define Hn   256
#define FOUT 128
#define KBB  384
#define NT1  1024   // phase-1 threads (16 waves)
#define BPW  2      // batch rows per workgroup (halves per-XCD L2 weight traffic)

// packed weight layout in d_ws (halves):
//   Wb_p [48][256][8]  -> 98304
//   W4_p [32][1024][8] -> 262144   (N = [ff1|ff2|ta|tb])
//   Wo_p [32][128][8]  -> 32768
//   hbuf [B*S*H] fp16  -> 33554432 (only if ws_size permits)
#define WB_OFF 0
#define W4_OFF 98304
#define WO_OFF 360448
#define WS_HALVES 393216
#define HBUF_OFF WS_HALVES
#define WS_SPLIT_BYTES ((size_t)(WS_HALVES + (size_t)Bn * Sn * Hn) * 2)

typedef _Float16 h2 __attribute__((ext_vector_type(2)));
typedef _Float16 h8 __attribute__((ext_vector_type(8)));

__device__ __forceinline__ float dot2f(h2 a, h2 b, float c) {
#if __has_builtin(__builtin_amdgcn_fdot2)
  return __builtin_amdgcn_fdot2(a, b, c, false);   // v_dot2_f32_f16
#else
  return c + (float)a[0] * (float)b[0] + (float)a[1] * (float)b[1];
#endif
}
__device__ __forceinline__ void dot8_4(h8 v, h8 w, float& c0, float& c1, float& c2, float& c3) {
  h2 v0 = {v[0], v[1]}, v1 = {v[2], v[3]}, v2 = {v[4], v[5]}, v3 = {v[6], v[7]};
  h2 w0 = {w[0], w[1]}, w1 = {w[2], w[3]}, w2 = {w[4], w[5]}, w3 = {w[6], w[7]};
  c0 = dot2f(v0, w0, c0); c1 = dot2f(v1, w1, c1);
  c2 = dot2f(v2, w2, c2); c3 = dot2f(v3, w3, c3);
}

// fp32 -> fp16 packing (verified layout from round 1)
__global__ __launch_bounds__(256) void pack_w(
    const float* __restrict__ Wb, const float* __restrict__ W1,
    const float* __restrict__ W2, const float* __restrict__ W3,
    const float* __restrict__ W4, const float* __restrict__ Wo,
    _Float16* __restrict__ ws) {
  int p = blockIdx.x * 256 + threadIdx.x;
  if (p >= WS_HALVES) return;
  float v;
  if (p < W4_OFF) {                       // backbone [384,256] row-major
    int r = p & 7, j = (p >> 3) & 255;
    int k = ((p >> 11) << 3) | r;
    v = Wb[k * 256 + j];
  } else if (p < WO_OFF) {                // heads concat: N = [ff1|ff2|ta|tb]
    int q = p - W4_OFF;
    int r = q & 7, j = (q >> 3) & 1023;
    int k = ((q >> 13) << 3) | r;
    int jj = j & 255;
    const float* Ws = (j < 256) ? W1 : (j < 512) ? W2 : (j < 768) ? W3 : W4;
    v = Ws[k * 256 + jj];
  } else {                                // Wout [256,128]
    int q = p - WO_OFF;
    int r = q & 7, j = (q >> 3) & 127;
    int k = ((q >> 10) << 3) | r;
    v = Wo[k * 128 + j];
  }
  ws[p] = (_Float16)v;
}

// Phase 1: one 1024-thread WG per PAIR of batch elements (BPW=2). Each 16B
// weight load now feeds two dot8_4 (rows b0,b1) -> 2x arithmetic intensity,
// and only 64 WGs stream weights from L2 (8/XCD instead of 16/XCD), halving
// the per-XCD L2 weight bandwidth demand that bounded the previous version.
// Weight streaming pattern itself unchanged (1 KB contiguous per wave-load,
// unroll-4, K-split with LDS reduction).
template <int INLINE_Y>
__global__ __launch_bounds__(NT1, 4) void cfc3(
    const float* __restrict__ x, const float* __restrict__ ts,
    const float* __restrict__ bb, const float* __restrict__ bf1,
    const float* __restrict__ bf2, const float* __restrict__ bta,
    const float* __restrict__ btb, const float* __restrict__ bo,
    _Float16* __restrict__ ws, float* __restrict__ out) {
  __shared__ __align__(16) _Float16 xh[BPW * KBB];   // per row: [0,128)=x_t [128,384)=h
  __shared__ __align__(16) _Float16 zf[BPW * Hn];
  __shared__ float tsb[BPW * Sn];
  __shared__ float scrZ[BPW * 768];
  __shared__ float scrH[BPW * 768];
  __shared__ float scrY[BPW * 896];

  const int tid = threadIdx.x;
  const int b0 = blockIdx.x * BPW;
  const _Float16* Wb_p = ws + WB_OFF;
  const _Float16* W4_p = ws + W4_OFF;
  const _Float16* Wo_p = ws + WO_OFF;
  _Float16* hbuf = ws + HBUF_OFF;

  const float* xrow0 = x + (size_t)b0 * Sn * FIN;
  const float* xrow1 = xrow0 + (size_t)Sn * FIN;
  const float* tsr0  = ts + (size_t)b0 * Sn;
  const float* tsr1  = tsr0 + Sn;
  float*       orow0 = out + (size_t)b0 * Sn * FOUT;
  float*       orow1 = orow0 + (size_t)Sn * FOUT;

  // ---- one-time staging ----
  tsb[tid]      = tsr0[tid];                   // NT1 == Sn
  tsb[Sn + tid] = tsr1[tid];
  if (tid < 256) {                             // h0 = 0 for both rows
    int r = tid >> 7, i = tid & 127;           // halves [128,384) of row r
    ((unsigned*)xh)[r * 192 + 64 + i] = 0;
  }
  if (tid < 128) {                             // x(0) both rows
    int r = tid >> 6, i = tid & 63;
    const float* xr = r ? xrow1 : xrow0;
    float2 xv = *(const float2*)(xr + 2 * i);
    h2 p; p[0] = (_Float16)xv.x; p[1] = (_Float16)xv.y;
    *(h2*)&xh[r * KBB + 2 * i] = p;
  }

  // ---- per-role constants ----
  const int jq = tid & 255;          // column within a 256 group
  const int kw = tid >> 8;           // Z K-split group (0..3), wave-uniform
  const float bbj = (tid < 256) ? bb[tid] : 0.f;
  const float bH = (kw == 0 ? bf1 : kw == 1 ? bf2 : kw == 2 ? bta : btb)[jq];
  const int jY = tid & 127, kq = tid >> 7;
  const float boj = (tid < 128) ? bo[tid] : 0.f;

  const _Float16* gZ = Wb_p + ((size_t)(kw * 12) * 256 + jq) * 8;  // 12 chunks
  const _Float16* gH = W4_p + (size_t)tid * 8;                     // 32 chunks
  const _Float16* gY = Wo_p + ((size_t)(kq * 4) * 128 + jY) * 8;   // 4 chunks
  __syncthreads();

  for (int st = 0; st < Sn; ++st) {
    // x(t+1) prefetch (threads 896..1023: 64 lanes per row)
    float2 xv; xv.x = 0.f; xv.y = 0.f;
    int pr = 0, pi = 0;
    if (tid >= 896 && st + 1 < Sn) {
      int u = tid - 896; pr = u >> 6; pi = u & 63;
      const float* xr = pr ? xrow1 : xrow0;
      xv = *(const float2*)(xr + (size_t)(st + 1) * FIN + 2 * pi);
    }

    // ---- Z: z = tanh([x,h] @ Wb + bb); K=384 split into 4 wave-groups ----
    float a00 = 0.f, a01 = 0.f, a02 = 0.f, a03 = 0.f;
    float a10 = 0.f, a11 = 0.f, a12 = 0.f, a13 = 0.f;
#pragma unroll 4
    for (int c = 0; c < 12; ++c) {
      h8 w  = *(const h8*)(gZ + (size_t)c * 2048);       // 1 KB/wave contiguous
      h8 v0 = *(const h8*)&xh[(kw * 12 + c) * 8];        // LDS broadcast row 0
      h8 v1 = *(const h8*)&xh[KBB + (kw * 12 + c) * 8];  // LDS broadcast row 1
      dot8_4(v0, w, a00, a01, a02, a03);
      dot8_4(v1, w, a10, a11, a12, a13);
    }
    float zs0 = a00 + a01 + a02 + a03;
    float zs1 = a10 + a11 + a12 + a13;
    if (tid >= 256) {
      scrZ[tid - 256]       = zs0;
      scrZ[768 + tid - 256] = zs1;
    }
    __syncthreads();                     // B1: Z xh-reads done, scrZ ready
    if (tid < 256) {
      float zp0 = zs0 + scrZ[tid] + scrZ[256 + tid] + scrZ[512 + tid] + bbj;
      float zp1 = zs1 + scrZ[768 + tid] + scrZ[1024 + tid] + scrZ[1280 + tid] + bbj;
      zf[tid]       = (_Float16)tanhf(zp0);
      zf[256 + tid] = (_Float16)tanhf(zp1);
    }
    if (tid >= 896 && st + 1 < Sn) {     // commit x(t+1); safe after B1
      h2 p; p[0] = (_Float16)xv.x; p[1] = (_Float16)xv.y;
      *(h2*)&xh[pr * KBB + 2 * pi] = p;
    }
    __syncthreads();                     // B2: zf ready

    // ---- H: col n = tid of [ff1|ff2|ta|tb], K=256, both rows ----
    float c00 = 0.f, c01 = 0.f, c02 = 0.f, c03 = 0.f;
    float c10 = 0.f, c11 = 0.f, c12 = 0.f, c13 = 0.f;
#pragma unroll 4
    for (int c = 0; c < 32; ++c) {
      h8 w  = *(const h8*)(gH + (size_t)c * 8192);       // 1 KB/wave contiguous
      h8 v0 = *(const h8*)&zf[c * 8];                    // LDS broadcast row 0
      h8 v1 = *(const h8*)&zf[256 + c * 8];              // LDS broadcast row 1
      dot8_4(v0, w, c00, c01, c02, c03);
      dot8_4(v1, w, c10, c11, c12, c13);
    }
    float g0 = c00 + c01 + c02 + c03 + bH;
    float g1 = c10 + c11 + c12 + c13 + bH;
    if (tid >= 256) {
      scrH[tid - 256]       = g0;
      scrH[768 + tid - 256] = g1;
    }
    __syncthreads();                     // B3: scrH ready
    if (tid < 256) {
      float tt0 = tsb[st], tt1 = tsb[Sn + st];
      // row 0
      float f2a = scrH[tid], taa = scrH[256 + tid], tba = scrH[512 + tid];
      float sg0 = 1.f / (1.f + __expf(-(taa * tt0 + tba)));
      float hn0 = tanhf(g0) * (1.f - sg0) + sg0 * tanhf(f2a);
      // row 1
      float f2b = scrH[768 + tid], tab = scrH[1024 + tid], tbb = scrH[1280 + tid];
      float sg1 = 1.f / (1.f + __expf(-(tab * tt1 + tbb)));
      float hn1 = tanhf(g1) * (1.f - sg1) + sg1 * tanhf(f2b);
      xh[128 + tid]       = (_Float16)hn0;
      xh[KBB + 128 + tid] = (_Float16)hn1;
      if (!INLINE_Y) {
        hbuf[((size_t)b0 * Sn + st) * Hn + tid]       = (_Float16)hn0;
        hbuf[((size_t)(b0 + 1) * Sn + st) * Hn + tid] = (_Float16)hn1;
      }
    }
    __syncthreads();                     // B4: h ready

    if (INLINE_Y) {
      // ---- Y: y = h @ Wout + bo, K split 8 ways, both rows ----
      float y00 = 0.f, y01 = 0.f, y02 = 0.f, y03 = 0.f;
      float y10 = 0.f, y11 = 0.f, y12 = 0.f, y13 = 0.f;
#pragma unroll
      for (int c = 0; c < 4; ++c) {
        h8 w  = *(const h8*)(gY + (size_t)c * 1024);
        h8 v0 = *(const h8*)&xh[128 + (kq * 4 + c) * 8];
        h8 v1 = *(const h8*)&xh[KBB + 128 + (kq * 4 + c) * 8];
        dot8_4(v0, w, y00, y01, y02, y03);
        dot8_4(v1, w, y10, y11, y12, y13);
      }
      float ys0 = y00 + y01 + y02 + y03;
      float ys1 = y10 + y11 + y12 + y13;
      if (tid >= 128) {
        scrY[tid - 128]       = ys0;
        scrY[896 + tid - 128] = ys1;
      }
      __syncthreads();                   // B5
      if (tid < 128) {
        float y0 = ys0 + boj, y1 = ys1 + boj;
#pragma unroll
        for (int p = 0; p < 7; ++p) {
          y0 += scrY[128 * p + tid];
          y1 += scrY[896 + 128 * p + tid];
        }
        orow0[(size_t)st * FOUT + tid] = y0;
        orow1[(size_t)st * FOUT + tid] = y1;
      }
    }
  }
}

// Phase 2 (split path): y[BS,128] = h[BS,256] @ Wout + bo. Wout LDS-resident,
// h rows staged 8 at a time; 512 WGs x 256 threads over all 256 CUs.
#define SMEMY (65536 + 4096)
extern "C" __global__ __launch_bounds__(256, 4)
void ygemm(const _Float16* __restrict__ ws, const float* __restrict__ bo,
           float* __restrict__ out) {
  extern __shared__ char ysm[];
  _Float16* sWo = (_Float16*)ysm;            // 32768 halves
  _Float16* sH  = (_Float16*)(ysm + 65536);  // 8 x 256 halves
  const int tid = threadIdx.x;
  { const uint4* g = (const uint4*)(ws + WO_OFF);
    uint4* l = (uint4*)sWo;
#pragma unroll
    for (int i = 0; i < 16; ++i) l[tid + 256 * i] = g[tid + 256 * i]; }
  const _Float16* hb = ws + HBUF_OFF;
  const int row0 = blockIdx.x * 256;
  const int j = tid & 127, rh = tid >> 7;
  const float boj = bo[j];
  for (int it = 0; it < 32; ++it) {
    const int rbase = row0 + it * 8;
    __syncthreads();                         // sH reads from prev iter done
    ((uint4*)sH)[tid] = ((const uint4*)(hb + (size_t)rbase * 256))[tid];
    __syncthreads();
#pragma unroll
    for (int rr = rh; rr < 8; rr += 2) {
      float y0 = 0.f, y1 = 0.f, y2 = 0.f, y3 = 0.f;
#pragma unroll 4
      for (int c = 0; c < 32; ++c) {
        h8 v = *(const h8*)&sH[rr * 256 + c * 8];       // broadcast
        h8 w = *(const h8*)&sWo[((size_t)c * 128 + j) * 8];
        dot8_4(v, w, y0, y1, y2, y3);
      }
      out[(size_t)(rbase + rr) * 128 + j] = y0 + y1 + y2 + y3 + boj;
    }
  }
}

extern "C" void kernel_launch(void* const* d_in, const int* in_sizes, int n_in,
                              void* d_out, int out_size, void* d_ws, size_t ws_size,
                              hipStream_t stream) {
  const float* x   = (const float*)d_in[0];
  const float* ts  = (const float*)d_in[1];
  const float* Wb  = (const float*)d_in[2];
  const float* bb  = (const float*)d_in[3];
  const float* W1  = (const float*)d_in[4];
  const float* bf1 = (const float*)d_in[5];
  const float* W2  = (const float*)d_in[6];
  const float* bf2 = (const float*)d_in[7];
  const float* W3  = (const float*)d_in[8];
  const float* bta = (const float*)d_in[9];
  const float* W4  = (const float*)d_in[10];
  const float* btb = (const float*)d_in[11];
  const float* Wo  = (const float*)d_in[12];
  const float* bo  = (const float*)d_in[13];
  float* out = (float*)d_out;
  _Float16* ws = (_Float16*)d_ws;

  pack_w<<<WS_HALVES / 256, 256, 0, stream>>>(Wb, W1, W2, W3, W4, Wo, ws);

  if (ws_size >= WS_SPLIT_BYTES) {
    cfc3<0><<<Bn / BPW, NT1, 0, stream>>>(x, ts, bb, bf1, bf2, bta, btb, bo, ws, out);
    hipFuncSetAttribute((const void*)ygemm,
                        hipFuncAttributeMaxDynamicSharedMemorySize, SMEMY);
    ygemm<<<(Bn * Sn) / 256, 256, SMEMY, stream>>>(ws, bo, out);
  } else {
    cfc3<1><<<Bn / BPW, NT1, 0, stream>>>(x, ts, bb, bf1, bf2, bta, btb, bo, ws, out);
  }
}

// Round 2
// 4582.050 us; speedup vs baseline: 1.6629x; 1.6629x over previous
//
#include <hip/hip_runtime.h>

// B=128, S=1024, F_IN=128, H=256, BB=256, F_OUT=128
#define Bn   128
#define Sn   1024
#define FIN  128
#define Hn   256
#define FOUT 128
#define KBB  384
#define NT1  1024   // phase-1 threads (16 waves)

// H-loop chunk partition (32 chunks of 16B per thread):
//   c in [0,NV)        -> VGPR-resident (loaded once)      NV*4 VGPRs
//   c in [NV,NV+NL)    -> LDS-resident (loaded once)       NL*16KB dynamic smem
//   c in [NV+NL,32)    -> streamed from L2 every step
#define NV 16
#define NL 8
#define DYN_SMEM (NL * 1024 * 8 * 2)   // 131072 bytes

// packed weight layout in d_ws (halves):
//   Wb_p [48][256][8]  -> 98304
//   W4_p [32][1024][8] -> 262144   (N = [ff1|ff2|ta|tb])
//   Wo_p [32][128][8]  -> 32768
//   hbuf [B*S*H] fp16  -> 33554432 (only if ws_size permits)
#define WB_OFF 0
#define W4_OFF 98304
#define WO_OFF 360448
#define WS_HALVES 393216
#define HBUF_OFF WS_HALVES
#define WS_SPLIT_BYTES ((size_t)(WS_HALVES + (size_t)Bn * Sn * Hn) * 2)

typedef _Float16 h2 __attribute__((ext_vector_type(2)));
typedef _Float16 h8 __attribute__((ext_vector_type(8)));

__device__ __forceinline__ float dot2f(h2 a, h2 b, float c) {
#if __has_builtin(__builtin_amdgcn_fdot2)
  return __builtin_amdgcn_fdot2(a, b, c, false);   // v_dot2_f32_f16
#else
  return c + (float)a[0] * (float)b[0] + (float)a[1] * (float)b[1];
#endif
}
__device__ __forceinline__ void dot8_4(h8 v, h8 w, float& c0, float& c1, float& c2, float& c3) {
  h2 v0 = {v[0], v[1]}, v1 = {v[2], v[3]}, v2 = {v[4], v[5]}, v3 = {v[6], v[7]};
  h2 w0 = {w[0], w[1]}, w1 = {w[2], w[3]}, w2 = {w[4], w[5]}, w3 = {w[6], w[7]};
  c0 = dot2f(v0, w0, c0); c1 = dot2f(v1, w1, c1);
  c2 = dot2f(v2, w2, c2); c3 = dot2f(v3, w3, c3);
}

// fp32 -> fp16 packing (verified layout)
__global__ __launch_bounds__(256) void pack_w(
    const float* __restrict__ Wb, const float* __restrict__ W1,
    const float* __restrict__ W2, const float* __restrict__ W3,
    const float* __restrict__ W4, const float* __restrict__ Wo,
    _Float16* __restrict__ ws) {
  int p = blockIdx.x * 256 + threadIdx.x;
  if (p >= WS_HALVES) return;
  float v;
  if (p < W4_OFF) {                       // backbone [384,256] row-major
    int r = p & 7, j = (p >> 3) & 255;
    int k = ((p >> 11) << 3) | r;
    v = Wb[k * 256 + j];
  } else if (p < WO_OFF) {                // heads concat: N = [ff1|ff2|ta|tb]
    int q = p - W4_OFF;
    int r = q & 7, j = (q >> 3) & 1023;
    int k = ((q >> 13) << 3) | r;
    int jj = j & 255;
    const float* Ws = (j < 256) ? W1 : (j < 512) ? W2 : (j < 768) ? W3 : W4;
    v = Ws[k * 256 + jj];
  } else {                                // Wout [256,128]
    int q = p - WO_OFF;
    int r = q & 7, j = (q >> 3) & 127;
    int k = ((q >> 10) << 3) | r;
    v = Wo[k * 128 + j];
  }
  ws[p] = (_Float16)v;
}

// Phase 1: one 1024-thread WG per batch element. The measured bottleneck
// (round 1) is the per-CU L2 port: 704 KB of weights streamed per step ≈
// 4.6 µs at ~64 B/cy/CU. Fix: make 384 KB/CU of W4 resident (16 chunks in
// VGPRs = 256 KB/CU + 8 chunks in LDS = 128 KB/CU, loaded once, reused for
// all 1024 steps); stream only 8 H-chunks + 12 Z-chunks = 320 KB/step.
// H-loop accumulation order: reg -> LDS -> streamed, so the fp-add chain
// does low-latency work while the L2 loads are in flight.
template <int INLINE_Y>
__global__ __launch_bounds__(NT1, 4) void cfc3(
    const float* __restrict__ x, const float* __restrict__ ts,
    const float* __restrict__ bb, const float* __restrict__ bf1,
    const float* __restrict__ bf2, const float* __restrict__ bta,
    const float* __restrict__ btb, const float* __restrict__ bo,
    _Float16* __restrict__ ws, float* __restrict__ out) {
  __shared__ __align__(16) _Float16 xh[KBB];   // [0,128): x_t  [128,384): h
  __shared__ __align__(16) _Float16 zf[Hn];
  __shared__ float tsb[Sn];
  __shared__ float scrZ[768];
  __shared__ float scrH[768];
  __shared__ float scrY[896];
  extern __shared__ _Float16 sWH[];            // [NL][1024][8] halves

  const int tid = threadIdx.x;
  const int b = blockIdx.x;
  const _Float16* Wb_p = ws + WB_OFF;
  const _Float16* W4_p = ws + W4_OFF;
  const _Float16* Wo_p = ws + WO_OFF;
  _Float16* hbuf = ws + HBUF_OFF;

  const float* xrow  = x  + (size_t)b * Sn * FIN;
  const float* tsrow = ts + (size_t)b * Sn;
  float*       orow  = out + (size_t)b * Sn * FOUT;

  // ---- per-role constants ----
  const int jq = tid & 255;          // column within a 256 group
  const int kw = tid >> 8;           // Z K-split group (0..3), wave-uniform
  const float bbj = (tid < 256) ? bb[tid] : 0.f;
  const float bH = (kw == 0 ? bf1 : kw == 1 ? bf2 : kw == 2 ? bta : btb)[jq];
  const int jY = tid & 127, kq = tid >> 7;
  const float boj = (tid < 128) ? bo[tid] : 0.f;

  const _Float16* gZ = Wb_p + ((size_t)(kw * 12) * 256 + jq) * 8;  // 12 chunks
  const _Float16* gH = W4_p + (size_t)tid * 8;                     // 32 chunks
  const _Float16* gY = Wo_p + ((size_t)(kq * 4) * 128 + jY) * 8;   // 4 chunks

  // ---- one-time weight residency ----
  h8 wH[NV];                                  // chunks [0,NV) in VGPRs
#pragma unroll
  for (int c = 0; c < NV; ++c) wH[c] = *(const h8*)(gH + (size_t)c * 8192);
#pragma unroll
  for (int cc = 0; cc < NL; ++cc)             // chunks [NV,NV+NL) in LDS
    *(h8*)(sWH + (size_t)cc * 8192 + tid * 8) =
        *(const h8*)(gH + (size_t)(NV + cc) * 8192);

  // ---- one-time staging ----
  tsb[tid] = tsrow[tid];                       // NT1 == Sn
  if (tid < 128) ((unsigned*)xh)[64 + tid] = 0;   // h0 = 0 (halves [128,384))
  if (tid < 64) {                              // x(0)
    float2 xv = *(const float2*)(xrow + 2 * tid);
    h2 p; p[0] = (_Float16)xv.x; p[1] = (_Float16)xv.y;
    *(h2*)&xh[2 * tid] = p;
  }
  __syncthreads();

  for (int st = 0; st < Sn; ++st) {
    // x(t+1) prefetch (wave 15)
    float2 xv; xv.x = 0.f; xv.y = 0.f;
    if (tid >= 960 && st + 1 < Sn)
      xv = *(const float2*)(xrow + (size_t)(st + 1) * FIN + 2 * (tid - 960));

    // ---- Z: z = tanh([x,h] @ Wb + bb); K=384 split into 4 wave-groups ----
    float a0 = 0.f, a1 = 0.f, a2 = 0.f, a3 = 0.f;
#pragma unroll 4
    for (int c = 0; c < 12; ++c) {
      h8 v = *(const h8*)&xh[(kw * 12 + c) * 8];        // LDS broadcast
      h8 w = *(const h8*)(gZ + (size_t)c * 2048);       // 1 KB/wave contiguous
      dot8_4(v, w, a0, a1, a2, a3);
    }
    float zs = a0 + a1 + a2 + a3;
    if (tid >= 256) scrZ[tid - 256] = zs;
    __syncthreads();                     // B1: Z xh-reads done, scrZ ready
    if (tid < 256) {
      float zp = zs + scrZ[tid] + scrZ[256 + tid] + scrZ[512 + tid] + bbj;
      zf[tid] = (_Float16)tanhf(zp);
    }
    if (tid >= 960 && st + 1 < Sn) {     // commit x(t+1); safe after B1
      h2 p; p[0] = (_Float16)xv.x; p[1] = (_Float16)xv.y;
      *(h2*)&xh[2 * (tid - 960)] = p;
    }
    __syncthreads();                     // B2: zf ready

    // ---- H: col n = tid of [ff1|ff2|ta|tb], K=256 ----
    float b0 = 0.f, b1 = 0.f, b2 = 0.f, b3 = 0.f;
    // VGPR-resident chunks first (keeps the fp-add chain busy while the
    // streamed loads below are in flight; loads have no ordering constraint)
#pragma unroll
    for (int c = 0; c < NV; ++c) {
      h8 v = *(const h8*)&zf[c * 8];                    // LDS broadcast
      dot8_4(v, wH[c], b0, b1, b2, b3);
    }
    // LDS-resident chunks
#pragma unroll
    for (int cc = 0; cc < NL; ++cc) {
      h8 v = *(const h8*)&zf[(NV + cc) * 8];
      h8 w = *(const h8*)(sWH + (size_t)cc * 8192 + tid * 8);
      dot8_4(v, w, b0, b1, b2, b3);
    }
    // streamed chunks
#pragma unroll 4
    for (int c = NV + NL; c < 32; ++c) {
      h8 v = *(const h8*)&zf[c * 8];
      h8 w = *(const h8*)(gH + (size_t)c * 8192);       // 1 KB/wave contiguous
      dot8_4(v, w, b0, b1, b2, b3);
    }
    float g = b0 + b1 + b2 + b3 + bH;
    if (tid >= 256) scrH[tid - 256] = g;
    __syncthreads();                     // B3: scrH ready
    if (tid < 256) {
      float ff2 = scrH[tid], ta = scrH[256 + tid], tb = scrH[512 + tid];
      float tt = tsb[st];
      float sg = 1.f / (1.f + __expf(-(ta * tt + tb)));
      float hn = tanhf(g) * (1.f - sg) + sg * tanhf(ff2);
      xh[128 + tid] = (_Float16)hn;
      if (!INLINE_Y)
        hbuf[((size_t)b * Sn + st) * Hn + tid] = (_Float16)hn;
    }
    __syncthreads();                     // B4: h ready

    if (INLINE_Y) {
      // ---- Y: y = h @ Wout + bo, K split 8 ways ----
      float y0 = 0.f, y1 = 0.f, y2 = 0.f, y3 = 0.f;
#pragma unroll
      for (int c = 0; c < 4; ++c) {
        h8 v = *(const h8*)&xh[128 + (kq * 4 + c) * 8];
        h8 w = *(const h8*)(gY + (size_t)c * 1024);
        dot8_4(v, w, y0, y1, y2, y3);
      }
      float ys = y0 + y1 + y2 + y3;
      if (tid >= 128) scrY[tid - 128] = ys;
      __syncthreads();                   // B5
      if (tid < 128) {
        float y = ys + boj;
#pragma unroll
        for (int p = 0; p < 7; ++p) y += scrY[128 * p + tid];
        orow[(size_t)st * FOUT + tid] = y;
      }
    }
  }
}

// Phase 2 (split path): y[BS,128] = h[BS,256] @ Wout + bo. Wout LDS-resident,
// h rows staged 8 at a time; 512 WGs x 256 threads over all 256 CUs.
#define SMEMY (65536 + 4096)
extern "C" __global__ __launch_bounds__(256, 4)
void ygemm(const _Float16* __restrict__ ws, const float* __restrict__ bo,
           float* __restrict__ out) {
  extern __shared__ char ysm[];
  _Float16* sWo = (_Float16*)ysm;            // 32768 halves
  _Float16* sH  = (_Float16*)(ysm + 65536);  // 8 x 256 halves
  const int tid = threadIdx.x;
  { const uint4* g = (const uint4*)(ws + WO_OFF);
    uint4* l = (uint4*)sWo;
#pragma unroll
    for (int i = 0; i < 16; ++i) l[tid + 256 * i] = g[tid + 256 * i]; }
  const _Float16* hb = ws + HBUF_OFF;
  const int row0 = blockIdx.x * 256;
  const int j = tid & 127, rh = tid >> 7;
  const float boj = bo[j];
  for (int it = 0; it < 32; ++it) {
    const int rbase = row0 + it * 8;
    __syncthreads();                         // sH reads from prev iter done
    ((uint4*)sH)[tid] = ((const uint4*)(hb + (size_t)rbase * 256))[tid];
    __syncthreads();
#pragma unroll
    for (int rr = rh; rr < 8; rr += 2) {
      float y0 = 0.f, y1 = 0.f, y2 = 0.f, y3 = 0.f;
#pragma unroll 4
      for (int c = 0; c < 32; ++c) {
        h8 v = *(const h8*)&sH[rr * 256 + c * 8];       // broadcast
        h8 w = *(const h8*)&sWo[((size_t)c * 128 + j) * 8];
        dot8_4(v, w, y0, y1, y2, y3);
      }
      out[(size_t)(rbase + rr) * 128 + j] = y0 + y1 + y2 + y3 + boj;
    }
  }
}

extern "C" void kernel_launch(void* const* d_in, const int* in_sizes, int n_in,
                              void* d_out, int out_size, void* d_ws, size_t ws_size,
                              hipStream_t stream) {
  const float* x   = (const float*)d_in[0];
  const float* ts  = (const float*)d_in[1];
  const float* Wb  = (const float*)d_in[2];
  const float* bb  = (const float*)d_in[3];
  const float* W1  = (const float*)d_in[4];
  const float* bf1 = (const float*)d_in[5];
  const float* W2  = (const float*)d_in[6];
  const float* bf2 = (const float*)d_in[7];
  const float* W3  = (const float*)d_in[8];
  const float* bta = (const float*)d_in[9];
  const float* W4  = (const float*)d_in[10];
  const float* btb = (const float*)d_in[11];
  const float* Wo  = (const float*)d_in[12];
  const float* bo  = (const float*)d_in[13];
  float* out = (float*)d_out;
  _Float16* ws = (_Float16*)d_ws;

  pack_w<<<WS_HALVES / 256, 256, 0, stream>>>(Wb, W1, W2, W3, W4, Wo, ws);

  if (ws_size >= WS_SPLIT_BYTES) {
    hipFuncSetAttribute((const void*)(cfc3<0>),
                        hipFuncAttributeMaxDynamicSharedMemorySize, DYN_SMEM);
    cfc3<0><<<Bn, NT1, DYN_SMEM, stream>>>(x, ts, bb, bf1, bf2, bta, btb, bo, ws, out);
    hipFuncSetAttribute((const void*)ygemm,
                        hipFuncAttributeMaxDynamicSharedMemorySize, SMEMY);
    ygemm<<<(Bn * Sn) / 256, 256, SMEMY, stream>>>(ws, bo, out);
  } else {
    hipFuncSetAttribute((const void*)(cfc3<1>),
                        hipFuncAttributeMaxDynamicSharedMemorySize, DYN_SMEM);
    cfc3<1><<<Bn, NT1, DYN_SMEM, stream>>>(x, ts, bb, bf1, bf2, bta, btb, bo, ws, out);
  }
}